// Round 1
// baseline (216.619 us; speedup 1.0000x reference)
//
#include <hip/hip_runtime.h>
#include <hip/hip_bf16.h>

typedef __bf16 bf16_t;
typedef __bf16 bf16x8 __attribute__((ext_vector_type(8)));
typedef float  f32x4  __attribute__((ext_vector_type(4)));

// Problem constants
// B=8, T=S=512, D=1024, NUM_HEADS=16, REUSE=8, NEW=8, HD=64, PE_MAX=512
static constexpr int PEW = 1023;  // 2*PE_MAX-1

// ---------------- fp32 -> bf16 convert (8 elems/thread) ----------------
__global__ void k_convert(const float* __restrict__ src, bf16_t* __restrict__ dst, int n8) {
  int i = blockIdx.x * blockDim.x + threadIdx.x;
  if (i >= n8) return;
  const float4* p = reinterpret_cast<const float4*>(src) + 2 * (long)i;
  float4 a = p[0], b = p[1];
  bf16x8 o;
  o[0] = (bf16_t)a.x; o[1] = (bf16_t)a.y; o[2] = (bf16_t)a.z; o[3] = (bf16_t)a.w;
  o[4] = (bf16_t)b.x; o[5] = (bf16_t)b.y; o[6] = (bf16_t)b.z; o[7] = (bf16_t)b.w;
  reinterpret_cast<bf16x8*>(dst)[i] = o;
}

// ------------- transpose + convert: src fp32 [R][C] -> dst bf16 [C][ld_dst] -------------
// dst[c][dst_off + r] = src[r][c].  grid = (C/32, R/32), block = 256.
__global__ void k_transpose(const float* __restrict__ src, bf16_t* __restrict__ dst,
                            int C, int ld_dst, int dst_off) {
  __shared__ float tile[32][33];
  int c0 = blockIdx.x * 32, r0 = blockIdx.y * 32;
  int lx = threadIdx.x & 31, ly = threadIdx.x >> 5;  // 32 x 8
  #pragma unroll
  for (int i = 0; i < 32; i += 8)
    tile[ly + i][lx] = src[(long)(r0 + ly + i) * C + (c0 + lx)];
  __syncthreads();
  #pragma unroll
  for (int i = 0; i < 32; i += 8)
    dst[(long)(c0 + ly + i) * ld_dst + dst_off + (r0 + lx)] = (bf16_t)tile[lx][ly + i];
}

// ---------------- generic batched GEMM, C = A * B^T (+epilogue) ----------------
// A: [M][K] (bf16 row-major, or fp32 row-major if A_F32 — converted in-register)
// B: [N][K] bf16 row-major (i.e. B^T layout, K contiguous)
// per-wave 64x64 (4x4 frags of 16x16x32), block = WR x WC waves.
// batching: z -> (zb = z/ZN, zn = z%ZN); pointer offsets via element strides.
enum { EPI_NONE = 0, EPI_BIASN = 1, EPI_REL = 2 };

template<int WR, int WC, int EPI, bool A_F32, bool OUT_F32, bool WRITE_T>
__global__ __launch_bounds__(WR * WC * 64)
void k_gemm_bt(const void* __restrict__ A_, const bf16_t* __restrict__ B_,
               void* __restrict__ C_, const float* __restrict__ bias,
               int K, int lda, int ldb, int ldc, float scale,
               int ZN, long sAb, long sAn, long sBb, long sBn, long sCb, long sCn) {
  const int z  = blockIdx.z;
  const int zb = z / ZN, zn = z - zb * ZN;
  const int lane = threadIdx.x & 63;
  const int wid  = threadIdx.x >> 6;
  const int wr = wid / WC, wc = wid - wr * WC;
  const int m0 = blockIdx.x * (WR * 64) + wr * 64;
  const int n0 = blockIdx.y * (WC * 64) + wc * 64;
  const int lhi = lane >> 4, llo = lane & 15;

  const bf16_t* Ab = (const bf16_t*)A_ + zb * sAb + zn * sAn;
  const float*  Af = (const float*)A_  + zb * sAb + zn * sAn;
  const bf16_t* Bp = B_ + zb * sBb + zn * sBn;

  f32x4 acc[4][4] = {};

  for (int k0 = 0; k0 < K; k0 += 32) {
    const int kk = k0 + lhi * 8;
    bf16x8 a[4], b[4];
    #pragma unroll
    for (int mi = 0; mi < 4; ++mi) {
      const long row = m0 + mi * 16 + llo;
      if constexpr (A_F32) {
        const float4* p = reinterpret_cast<const float4*>(Af + row * lda + kk);
        float4 x = p[0], y = p[1];
        bf16x8 t;
        t[0] = (bf16_t)x.x; t[1] = (bf16_t)x.y; t[2] = (bf16_t)x.z; t[3] = (bf16_t)x.w;
        t[4] = (bf16_t)y.x; t[5] = (bf16_t)y.y; t[6] = (bf16_t)y.z; t[7] = (bf16_t)y.w;
        a[mi] = t;
      } else {
        a[mi] = *reinterpret_cast<const bf16x8*>(Ab + row * lda + kk);
      }
    }
    #pragma unroll
    for (int ni = 0; ni < 4; ++ni) {
      const long row = n0 + ni * 16 + llo;
      b[ni] = *reinterpret_cast<const bf16x8*>(Bp + row * ldb + kk);
    }
    #pragma unroll
    for (int mi = 0; mi < 4; ++mi)
      #pragma unroll
      for (int ni = 0; ni < 4; ++ni)
        acc[mi][ni] = __builtin_amdgcn_mfma_f32_16x16x32_bf16(a[mi], b[ni], acc[mi][ni], 0, 0, 0);
  }

  float*  Cf = (float*)C_;
  bf16_t* Cb = (bf16_t*)C_;
  const long coff = zb * sCb + zn * sCn;
  #pragma unroll
  for (int mi = 0; mi < 4; ++mi) {
    #pragma unroll
    for (int ni = 0; ni < 4; ++ni) {
      #pragma unroll
      for (int r = 0; r < 4; ++r) {
        const int m = m0 + mi * 16 + lhi * 4 + r;
        const int n = n0 + ni * 16 + llo;
        float v = acc[mi][ni][r];
        if constexpr (EPI == EPI_BIASN) v += bias[n];
        if constexpr (EPI == EPI_REL) {
          int idx = n - m + 511;                      // rel index, in [0,1022] here
          idx = idx < 0 ? 0 : (idx > PEW - 1 ? PEW - 1 : idx);
          v += bias[zn * PEW + idx];
        }
        v *= scale;
        if constexpr (OUT_F32)        Cf[coff + (long)m * ldc + n] = v;
        else if constexpr (!WRITE_T)  Cb[coff + (long)m * ldc + n] = (bf16_t)v;
        else                          Cb[coff + (long)n * ldc + m] = (bf16_t)v;
      }
    }
  }
}

// ---------------- in-place row softmax over bf16 logits (512 cols) ----------------
// one wave per row; block 256 = 4 rows.
__global__ void k_softmax(bf16_t* __restrict__ sc) {
  const int row  = blockIdx.x * 4 + (threadIdx.x >> 6);
  const int lane = threadIdx.x & 63;
  bf16x8* p = reinterpret_cast<bf16x8*>(sc + (long)row * 512) + lane;
  bf16x8 v = *p;
  float f[8];
  float mx = -1e30f;
  #pragma unroll
  for (int i = 0; i < 8; ++i) { f[i] = (float)v[i]; mx = fmaxf(mx, f[i]); }
  #pragma unroll
  for (int off = 32; off; off >>= 1) mx = fmaxf(mx, __shfl_xor(mx, off));
  float s = 0.f;
  #pragma unroll
  for (int i = 0; i < 8; ++i) { f[i] = __expf(f[i] - mx); s += f[i]; }
  #pragma unroll
  for (int off = 32; off; off >>= 1) s += __shfl_xor(s, off);
  const float inv = 1.f / s;
  bf16x8 o;
  #pragma unroll
  for (int i = 0; i < 8; ++i) o[i] = (bf16_t)(f[i] * inv);
  *p = o;
}

extern "C" void kernel_launch(void* const* d_in, const int* in_sizes, int n_in,
                              void* d_out, int out_size, void* d_ws, size_t ws_size,
                              hipStream_t stream) {
  const float* query = (const float*)d_in[0];   // [8,512,1024]
  const float* value = (const float*)d_in[1];   // [8,512,1024]
  const float* reuse = (const float*)d_in[2];   // [8,8,512,512]
  const float* Wq    = (const float*)d_in[3];   // [1024,8,64]
  const float* bq    = (const float*)d_in[4];   // [512]
  const float* Wk    = (const float*)d_in[5];
  const float* bk    = (const float*)d_in[6];
  const float* Wv    = (const float*)d_in[7];   // [1024,16,64]
  const float* bv    = (const float*)d_in[8];   // [1024]
  const float* pe    = (const float*)d_in[9];   // [1,8,1023]
  const float* WoR   = (const float*)d_in[10];  // [8,64,1024]
  const float* WoN   = (const float*)d_in[11];  // [8,64,1024]
  const float* bo    = (const float*)d_in[12];  // [1024]
  float* out = (float*)d_out;                   // [8,512,1024] fp32

  char* w = (char*)d_ws;
  bf16_t* qx  = (bf16_t*)(w);                    // [4096][1024]  8 MiB
  bf16_t* vx  = (bf16_t*)(w + (8L  << 20));      // [4096][1024]  8 MiB
  bf16_t* WqT = (bf16_t*)(w + (16L << 20));      // [512][1024]   1 MiB
  bf16_t* WkT = (bf16_t*)(w + (17L << 20));      // [512][1024]   1 MiB
  bf16_t* WvT = (bf16_t*)(w + (18L << 20));      // [1024][1024]  2 MiB
  bf16_t* WoT = (bf16_t*)(w + (20L << 20));      // [1024][1024]  2 MiB
  bf16_t* qb  = (bf16_t*)(w + (22L << 20));      // [4096][512]   4 MiB
  bf16_t* kb  = (bf16_t*)(w + (26L << 20));      // [4096][512]   4 MiB
  bf16_t* vbT = (bf16_t*)(w + (30L << 20));      // [1024][4096]  8 MiB
  bf16_t* sc  = (bf16_t*)(w + (38L << 20));      // [8][8][512][512] 32 MiB
  bf16_t* om  = (bf16_t*)(w + (70L << 20));      // [4096][1024]  8 MiB
  (void)ws_size; (void)in_sizes; (void)n_in; (void)out_size;

  // 1) convert activations to bf16
  k_convert<<<2048, 256, 0, stream>>>(query, qx, 524288);
  k_convert<<<2048, 256, 0, stream>>>(value, vx, 524288);

  // 2) transpose weights to [N][K] bf16
  k_transpose<<<dim3(16, 32), 256, 0, stream>>>(Wq,  WqT, 512,  1024, 0);
  k_transpose<<<dim3(16, 32), 256, 0, stream>>>(Wk,  WkT, 512,  1024, 0);
  k_transpose<<<dim3(32, 32), 256, 0, stream>>>(Wv,  WvT, 1024, 1024, 0);
  k_transpose<<<dim3(32, 16), 256, 0, stream>>>(WoR, WoT, 1024, 1024, 0);
  k_transpose<<<dim3(32, 16), 256, 0, stream>>>(WoN, WoT, 1024, 1024, 512);

  // 3) projections
  // qb = (qx @ WqT^T + bq) * 1/8        [4096][512]
  k_gemm_bt<2, 2, EPI_BIASN, false, false, false><<<dim3(32, 4, 1), 256, 0, stream>>>(
      qx, WqT, qb, bq, 1024, 1024, 1024, 512, 0.125f, 1, 0, 0, 0, 0, 0, 0);
  // kb = vx @ WkT^T + bk                [4096][512]
  k_gemm_bt<2, 2, EPI_BIASN, false, false, false><<<dim3(32, 4, 1), 256, 0, stream>>>(
      vx, WkT, kb, bk, 1024, 1024, 1024, 512, 1.f, 1, 0, 0, 0, 0, 0, 0);
  // vbT = (vx @ WvT^T + bv)^T           [1024][4096] (transposed write)
  k_gemm_bt<2, 2, EPI_BIASN, false, false, true><<<dim3(32, 8, 1), 256, 0, stream>>>(
      vx, WvT, vbT, bv, 1024, 1024, 1024, 4096, 1.f, 1, 0, 0, 0, 0, 0, 0);

  // 4) scores = qb_slice @ kb_slice^T + relpos bias  -> bf16 logits [b][n][512][512]
  k_gemm_bt<2, 2, EPI_REL, false, false, false><<<dim3(4, 4, 64), 256, 0, stream>>>(
      qb, kb, sc, pe, 64, 512, 512, 512, 1.f, 8,
      262144L, 64L, 262144L, 64L, 2097152L, 262144L);

  // 5) softmax in place (32768 rows of 512)
  k_softmax<<<8192, 256, 0, stream>>>(sc);

  // 6) out_mid[:, :512] = reuse_scores @ v_reuse   (A fp32, converted on load)
  k_gemm_bt<2, 1, EPI_NONE, true, false, false><<<dim3(4, 1, 64), 128, 0, stream>>>(
      reuse, vbT, om, nullptr, 512, 512, 4096, 1024, 1.f, 8,
      2097152L, 262144L, 512L, 262144L, 524288L, 64L);
  //    out_mid[:, 512:] = P @ v_new
  k_gemm_bt<2, 1, EPI_NONE, false, false, false><<<dim3(4, 1, 64), 128, 0, stream>>>(
      sc, vbT + (long)512 * 4096, om + 512, nullptr, 512, 512, 4096, 1024, 1.f, 8,
      2097152L, 262144L, 512L, 262144L, 524288L, 64L);

  // 7) out = out_mid @ WoT^T + bo  (fp32 out)
  k_gemm_bt<2, 2, EPI_BIASN, false, true, false><<<dim3(32, 8, 1), 256, 0, stream>>>(
      om, WoT, out, bo, 1024, 1024, 1024, 1024, 1.f, 1, 0, 0, 0, 0, 0, 0);
}

// Round 2
// 142.518 us; speedup vs baseline: 1.5199x; 1.5199x over previous
//
#include <hip/hip_runtime.h>
#include <hip/hip_bf16.h>

typedef __bf16 bf16_t;
typedef __bf16 bf16x8 __attribute__((ext_vector_type(8)));
typedef float  f32x4  __attribute__((ext_vector_type(4)));

static constexpr int PEW = 1023;  // 2*PE_MAX-1

enum { EPI_NONE = 0, EPI_BIASN = 1, EPI_REL = 2 };

#define GLDS(gsrc, ldst)                                                              \
  __builtin_amdgcn_global_load_lds(                                                   \
      (const __attribute__((address_space(1))) unsigned int*)(gsrc),                  \
      (__attribute__((address_space(3))) unsigned int*)(ldst), 16, 0, 0)

// ---------------- fused fp32->bf16 convert for query & value ----------------
__global__ void k_convert2(const float* __restrict__ a, bf16_t* __restrict__ da,
                           const float* __restrict__ b, bf16_t* __restrict__ db, int n8) {
  int i = blockIdx.x * blockDim.x + threadIdx.x;
  const float* s; bf16_t* d;
  if (i < n8) { s = a; d = da; } else { s = b; d = db; i -= n8; }
  const float4* p = reinterpret_cast<const float4*>(s) + 2 * (long)i;
  float4 x = p[0], y = p[1];
  bf16x8 o;
  o[0] = (bf16_t)x.x; o[1] = (bf16_t)x.y; o[2] = (bf16_t)x.z; o[3] = (bf16_t)x.w;
  o[4] = (bf16_t)y.x; o[5] = (bf16_t)y.y; o[6] = (bf16_t)y.z; o[7] = (bf16_t)y.w;
  reinterpret_cast<bf16x8*>(d)[i] = o;
}

// ---------------- merged 5-way weight transpose (+scale) ----------------
// dst[c][ld=1024 : off + r] = src[r][c] * scale
struct TArgs {
  const float* src[5];
  bf16_t* dst[5];
  int C[5], Ct[5], off[5], blk0[6];
  float scale[5];
};
__global__ void k_transpose5(TArgs ta) {
  __shared__ float tile[32][33];
  const int bid = blockIdx.x;
  int s = 0;
  while (bid >= ta.blk0[s + 1]) ++s;
  const int bi = bid - ta.blk0[s];
  const int Ct = ta.Ct[s];
  const int c0 = (bi % Ct) * 32, r0 = (bi / Ct) * 32;
  const int C = ta.C[s];
  const float* src = ta.src[s];
  const int lx = threadIdx.x & 31, ly = threadIdx.x >> 5;
  #pragma unroll
  for (int i = 0; i < 32; i += 8)
    tile[ly + i][lx] = src[(long)(r0 + ly + i) * C + (c0 + lx)];
  __syncthreads();
  const float sc = ta.scale[s];
  bf16_t* dst = ta.dst[s];
  const int off = ta.off[s];
  #pragma unroll
  for (int i = 0; i < 32; i += 8)
    dst[(long)(c0 + ly + i) * 1024 + off + (r0 + lx)] = (bf16_t)(tile[lx][ly + i] * sc);
}

// ---------------- m97-structure GEMM: (MI*32)x128 tile, BK=32, global_load_lds ----------------
// A [M][K] bf16, B [N][K] bf16 (B^T layout), 4 waves (2x2), wave tile (MI*16)x64.
template<int MI, int EPI, bool OUT_F32>
__global__ __launch_bounds__(256)
void k_gemm_st(const bf16_t* __restrict__ A_, const bf16_t* __restrict__ B_,
               void* __restrict__ C_, const float* __restrict__ bias,
               int K, int lda, int ldb, int ldc,
               int ZN, long sAb, long sAn, long sBb, long sBn, long sCb, long sCn) {
  __shared__ bf16_t lsA[MI * 1024];
  __shared__ bf16_t lsB[4096];
  const int z = blockIdx.z, zb = z / ZN, zn = z - zb * ZN;
  const int t = threadIdx.x, lane = t & 63, wid = t >> 6;
  const int wr = wid >> 1, wc = wid & 1;
  const int m0 = blockIdx.x * (MI * 32), n0 = blockIdx.y * 128;
  const int lhi = lane >> 4, llo = lane & 15;

  const bf16_t* Ab = A_ + zb * sAb + zn * sAn + (long)m0 * lda;
  const bf16_t* Bb = B_ + zb * sBb + zn * sBn + (long)n0 * ldb;

  const int e0 = t * 8,        r0s = e0 >> 5, c0s = e0 & 31;
  const int e1 = (256 + t) * 8, r1s = e1 >> 5, c1s = e1 & 31;
  bf16_t* lA0 = lsA + wid * 512;
  bf16_t* lA1 = lsA + 2048 + wid * 512;
  bf16_t* lB0 = lsB + wid * 512;
  bf16_t* lB1 = lsB + 2048 + wid * 512;

  f32x4 acc[MI][4] = {};

  for (int k0 = 0; k0 < K; k0 += 32) {
    GLDS(Ab + (long)r0s * lda + k0 + c0s, lA0);
    if constexpr (MI == 4) GLDS(Ab + (long)r1s * lda + k0 + c1s, lA1);
    GLDS(Bb + (long)r0s * ldb + k0 + c0s, lB0);
    GLDS(Bb + (long)r1s * ldb + k0 + c1s, lB1);
    __syncthreads();
    bf16x8 a[MI], b[4];
    #pragma unroll
    for (int mi = 0; mi < MI; ++mi)
      a[mi] = *reinterpret_cast<const bf16x8*>(lsA + (wr * (MI * 16) + mi * 16 + llo) * 32 + lhi * 8);
    #pragma unroll
    for (int ni = 0; ni < 4; ++ni)
      b[ni] = *reinterpret_cast<const bf16x8*>(lsB + (wc * 64 + ni * 16 + llo) * 32 + lhi * 8);
    #pragma unroll
    for (int mi = 0; mi < MI; ++mi)
      #pragma unroll
      for (int ni = 0; ni < 4; ++ni)
        acc[mi][ni] = __builtin_amdgcn_mfma_f32_16x16x32_bf16(a[mi], b[ni], acc[mi][ni], 0, 0, 0);
    __syncthreads();
  }

  float* Cf = (float*)C_;
  bf16_t* Cb = (bf16_t*)C_;
  const long coff = zb * sCb + zn * sCn;
  #pragma unroll
  for (int mi = 0; mi < MI; ++mi) {
    #pragma unroll
    for (int ni = 0; ni < 4; ++ni) {
      #pragma unroll
      for (int r = 0; r < 4; ++r) {
        const int m = m0 + wr * (MI * 16) + mi * 16 + lhi * 4 + r;
        const int n = n0 + wc * 64 + ni * 16 + llo;
        float v = acc[mi][ni][r];
        if constexpr (EPI == EPI_BIASN) v += bias[n];
        if constexpr (EPI == EPI_REL) {
          int idx = n - m + 511;
          idx = idx < 0 ? 0 : (idx > PEW - 1 ? PEW - 1 : idx);
          v += bias[zn * PEW + idx];
        }
        if constexpr (OUT_F32) Cf[coff + (long)m * ldc + n] = v;
        else                   Cb[coff + (long)m * ldc + n] = (bf16_t)v;
      }
    }
  }
}

// ---------------- packed projection GEMMs (qb | kb | vbT^T) in one launch ----------------
// all: M=4096, K=1024, lda=ldb=1024, 128x128 tiles, bf16 out, bias epilogue.
struct ProjItem {
  const bf16_t* A; const bf16_t* B; bf16_t* C; const float* bias;
  float bscale; int ldc; int Nt; int writeT;
};
struct ProjArgs { ProjItem it[3]; };

__global__ __launch_bounds__(256)
void k_gemm_proj(ProjArgs pa) {
  const ProjItem it = pa.it[blockIdx.z];
  if ((int)blockIdx.y >= it.Nt) return;
  __shared__ bf16_t lsA[4096];
  __shared__ bf16_t lsB[4096];
  const int t = threadIdx.x, lane = t & 63, wid = t >> 6;
  const int wr = wid >> 1, wc = wid & 1;
  const int m0 = blockIdx.x * 128, n0 = blockIdx.y * 128;
  const int lhi = lane >> 4, llo = lane & 15;

  const bf16_t* Ab = it.A + (long)m0 * 1024;
  const bf16_t* Bb = it.B + (long)n0 * 1024;

  const int e0 = t * 8,        r0s = e0 >> 5, c0s = e0 & 31;
  const int e1 = (256 + t) * 8, r1s = e1 >> 5, c1s = e1 & 31;
  bf16_t* lA0 = lsA + wid * 512;
  bf16_t* lA1 = lsA + 2048 + wid * 512;
  bf16_t* lB0 = lsB + wid * 512;
  bf16_t* lB1 = lsB + 2048 + wid * 512;

  f32x4 acc[4][4] = {};

  for (int k0 = 0; k0 < 1024; k0 += 32) {
    GLDS(Ab + (long)r0s * 1024 + k0 + c0s, lA0);
    GLDS(Ab + (long)r1s * 1024 + k0 + c1s, lA1);
    GLDS(Bb + (long)r0s * 1024 + k0 + c0s, lB0);
    GLDS(Bb + (long)r1s * 1024 + k0 + c1s, lB1);
    __syncthreads();
    bf16x8 a[4], b[4];
    #pragma unroll
    for (int mi = 0; mi < 4; ++mi)
      a[mi] = *reinterpret_cast<const bf16x8*>(lsA + (wr * 64 + mi * 16 + llo) * 32 + lhi * 8);
    #pragma unroll
    for (int ni = 0; ni < 4; ++ni)
      b[ni] = *reinterpret_cast<const bf16x8*>(lsB + (wc * 64 + ni * 16 + llo) * 32 + lhi * 8);
    #pragma unroll
    for (int mi = 0; mi < 4; ++mi)
      #pragma unroll
      for (int ni = 0; ni < 4; ++ni)
        acc[mi][ni] = __builtin_amdgcn_mfma_f32_16x16x32_bf16(a[mi], b[ni], acc[mi][ni], 0, 0, 0);
    __syncthreads();
  }

  #pragma unroll
  for (int mi = 0; mi < 4; ++mi) {
    #pragma unroll
    for (int ni = 0; ni < 4; ++ni) {
      #pragma unroll
      for (int r = 0; r < 4; ++r) {
        const int m = m0 + wr * 64 + mi * 16 + lhi * 4 + r;
        const int n = n0 + wc * 64 + ni * 16 + llo;
        float v = acc[mi][ni][r] + it.bias[n] * it.bscale;
        if (it.writeT) it.C[(long)n * it.ldc + m] = (bf16_t)v;
        else           it.C[(long)m * it.ldc + n] = (bf16_t)v;
      }
    }
  }
}

// ---------------- in-place row softmax over bf16 logits (512 cols) ----------------
__global__ void k_softmax(bf16_t* __restrict__ sc) {
  const int row  = blockIdx.x * 4 + (threadIdx.x >> 6);
  const int lane = threadIdx.x & 63;
  bf16x8* p = reinterpret_cast<bf16x8*>(sc + (long)row * 512) + lane;
  bf16x8 v = *p;
  float f[8];
  float mx = -1e30f;
  #pragma unroll
  for (int i = 0; i < 8; ++i) { f[i] = (float)v[i]; mx = fmaxf(mx, f[i]); }
  #pragma unroll
  for (int off = 32; off; off >>= 1) mx = fmaxf(mx, __shfl_xor(mx, off));
  float s = 0.f;
  #pragma unroll
  for (int i = 0; i < 8; ++i) { f[i] = __expf(f[i] - mx); s += f[i]; }
  #pragma unroll
  for (int off = 32; off; off >>= 1) s += __shfl_xor(s, off);
  const float inv = 1.f / s;
  bf16x8 o;
  #pragma unroll
  for (int i = 0; i < 8; ++i) o[i] = (bf16_t)(f[i] * inv);
  *p = o;
}

// ---------------- PV: out_mid = scores @ v  (reuse: fp32 A | new: bf16 A) in one launch ----------------
// per z: M=512 (T), N=64, K=512. block = 128 thr (2 waves), tile 128x64. grid (4,1,128).
__global__ __launch_bounds__(128)
void k_pv(const float* __restrict__ reuse, const bf16_t* __restrict__ sc,
          const bf16_t* __restrict__ vbT, bf16_t* __restrict__ om) {
  const int z = blockIdx.z;
  const bool isReuse = z < 64;
  const int zz = isReuse ? z : z - 64;
  const int b = zz >> 3, n = zz & 7;
  const int lane = threadIdx.x & 63, wid = threadIdx.x >> 6;
  const int m0 = blockIdx.x * 128 + wid * 64;
  const int lhi = lane >> 4, llo = lane & 15;

  const float*  Af = reuse + (long)b * 2097152 + (long)n * 262144;
  const bf16_t* Ab = sc    + (long)b * 2097152 + (long)n * 262144;
  const bf16_t* Bp = vbT + ((long)((isReuse ? 0 : 512) + n * 64)) * 4096 + b * 512;

  f32x4 acc[4][4] = {};

  for (int k0 = 0; k0 < 512; k0 += 32) {
    const int kk = k0 + lhi * 8;
    bf16x8 a[4], bfr[4];
    #pragma unroll
    for (int mi = 0; mi < 4; ++mi) {
      const long row = m0 + mi * 16 + llo;
      if (isReuse) {
        const float4* p = reinterpret_cast<const float4*>(Af + row * 512 + kk);
        float4 x = p[0], y = p[1];
        bf16x8 tv;
        tv[0] = (bf16_t)x.x; tv[1] = (bf16_t)x.y; tv[2] = (bf16_t)x.z; tv[3] = (bf16_t)x.w;
        tv[4] = (bf16_t)y.x; tv[5] = (bf16_t)y.y; tv[6] = (bf16_t)y.z; tv[7] = (bf16_t)y.w;
        a[mi] = tv;
      } else {
        a[mi] = *reinterpret_cast<const bf16x8*>(Ab + row * 512 + kk);
      }
    }
    #pragma unroll
    for (int ni = 0; ni < 4; ++ni)
      bfr[ni] = *reinterpret_cast<const bf16x8*>(Bp + (long)(ni * 16 + llo) * 4096 + kk);
    #pragma unroll
    for (int mi = 0; mi < 4; ++mi)
      #pragma unroll
      for (int ni = 0; ni < 4; ++ni)
        acc[mi][ni] = __builtin_amdgcn_mfma_f32_16x16x32_bf16(a[mi], bfr[ni], acc[mi][ni], 0, 0, 0);
  }

  bf16_t* Cb = om + (long)b * 524288 + (isReuse ? 0 : 512) + n * 64;
  #pragma unroll
  for (int mi = 0; mi < 4; ++mi) {
    #pragma unroll
    for (int ni = 0; ni < 4; ++ni) {
      #pragma unroll
      for (int r = 0; r < 4; ++r) {
        const int m = m0 + mi * 16 + lhi * 4 + r;
        const int nn = ni * 16 + llo;
        Cb[(long)m * 1024 + nn] = (bf16_t)acc[mi][ni][r];
      }
    }
  }
}

extern "C" void kernel_launch(void* const* d_in, const int* in_sizes, int n_in,
                              void* d_out, int out_size, void* d_ws, size_t ws_size,
                              hipStream_t stream) {
  const float* query = (const float*)d_in[0];
  const float* value = (const float*)d_in[1];
  const float* reuse = (const float*)d_in[2];
  const float* Wq    = (const float*)d_in[3];
  const float* bq    = (const float*)d_in[4];
  const float* Wk    = (const float*)d_in[5];
  const float* bk    = (const float*)d_in[6];
  const float* Wv    = (const float*)d_in[7];
  const float* bv    = (const float*)d_in[8];
  const float* pe    = (const float*)d_in[9];
  const float* WoR   = (const float*)d_in[10];
  const float* WoN   = (const float*)d_in[11];
  const float* bo    = (const float*)d_in[12];
  float* out = (float*)d_out;
  (void)in_sizes; (void)n_in; (void)out_size; (void)ws_size;

  char* w = (char*)d_ws;
  bf16_t* qx  = (bf16_t*)(w);                 // [4096][1024]
  bf16_t* vx  = (bf16_t*)(w + (8L  << 20));   // [4096][1024]
  bf16_t* WqT = (bf16_t*)(w + (16L << 20));   // [512][1024] (pre-scaled by 1/8)
  bf16_t* WkT = (bf16_t*)(w + (17L << 20));   // [512][1024]
  bf16_t* WvT = (bf16_t*)(w + (18L << 20));   // [1024][1024]
  bf16_t* WoT = (bf16_t*)(w + (20L << 20));   // [1024][1024]
  bf16_t* qb  = (bf16_t*)(w + (22L << 20));   // [4096][512]
  bf16_t* kb  = (bf16_t*)(w + (26L << 20));   // [4096][512]
  bf16_t* vbT = (bf16_t*)(w + (30L << 20));   // [1024][4096]
  bf16_t* sc  = (bf16_t*)(w + (38L << 20));   // [8][8][512][512]
  bf16_t* om  = (bf16_t*)(w + (70L << 20));   // [4096][1024]

  // 1) convert query+value to bf16 (single launch)
  k_convert2<<<4096, 256, 0, stream>>>(query, qx, value, vx, 524288);

  // 2) all weight transposes (single launch); q-scale folded into WqT
  TArgs ta;
  ta.src[0] = Wq;  ta.dst[0] = WqT; ta.C[0] = 512;  ta.Ct[0] = 16; ta.off[0] = 0;   ta.scale[0] = 0.125f;
  ta.src[1] = Wk;  ta.dst[1] = WkT; ta.C[1] = 512;  ta.Ct[1] = 16; ta.off[1] = 0;   ta.scale[1] = 1.f;
  ta.src[2] = Wv;  ta.dst[2] = WvT; ta.C[2] = 1024; ta.Ct[2] = 32; ta.off[2] = 0;   ta.scale[2] = 1.f;
  ta.src[3] = WoR; ta.dst[3] = WoT; ta.C[3] = 1024; ta.Ct[3] = 32; ta.off[3] = 0;   ta.scale[3] = 1.f;
  ta.src[4] = WoN; ta.dst[4] = WoT; ta.C[4] = 1024; ta.Ct[4] = 32; ta.off[4] = 512; ta.scale[4] = 1.f;
  ta.blk0[0] = 0; ta.blk0[1] = 512; ta.blk0[2] = 1024; ta.blk0[3] = 2048; ta.blk0[4] = 2560; ta.blk0[5] = 3072;
  k_transpose5<<<3072, 256, 0, stream>>>(ta);

  // 3) packed projections: qb = (qx@WqT^T)*? + bq/8 ; kb = vx@WkT^T + bk ; vbT = (vx@WvT^T + bv)^T
  ProjArgs pa;
  pa.it[0] = { qx, WqT, qb,  bq, 0.125f, 512,  4, 0 };
  pa.it[1] = { vx, WkT, kb,  bk, 1.f,    512,  4, 0 };
  pa.it[2] = { vx, WvT, vbT, bv, 1.f,    4096, 8, 1 };
  k_gemm_proj<<<dim3(32, 8, 3), 256, 0, stream>>>(pa);

  // 4) scores = qb_slice @ kb_slice^T + relpos bias -> bf16 logits [b][n][512][512]
  k_gemm_st<4, EPI_REL, false><<<dim3(4, 4, 64), 256, 0, stream>>>(
      qb, kb, sc, pe, 64, 512, 512, 512, 8,
      262144L, 64L, 262144L, 64L, 2097152L, 262144L);

  // 5) softmax in place (32768 rows of 512)
  k_softmax<<<8192, 256, 0, stream>>>(sc);

  // 6) out_mid = [reuse @ v_reuse | P @ v_new]   (one launch, 512 blocks)
  k_pv<<<dim3(4, 1, 128), 128, 0, stream>>>(reuse, sc, vbT, om);

  // 7) out = om @ WoT^T + bo (fp32 out), 64x128 tiles -> 512 blocks
  k_gemm_st<2, EPI_BIASN, true><<<dim3(64, 8, 1), 256, 0, stream>>>(
      om, WoT, out, bo, 1024, 1024, 1024, 1024, 1,
      0L, 0L, 0L, 0L, 0L, 0L);
}